// Round 1
// baseline (1436.496 us; speedup 1.0000x reference)
//
#include <hip/hip_runtime.h>
#include <hip/hip_bf16.h>
#include <math.h>

constexpr int B_ = 8, L_ = 256, D_ = 256, H_ = 8, DK_ = 32, NL_ = 4, V_ = 2048, FF_ = 1024;
constexpr int N_ = B_ * L_;
constexpr float EPS_ = 1e-5f;

// x[n,d] = value_tab[tok]*sqrt(D) + coord_tab[p%3] + pos_tab[p/3]
__global__ void embed_kernel(const int* __restrict__ tokens, const int* __restrict__ positions,
                             const float* __restrict__ vtab, const float* __restrict__ ctab,
                             const float* __restrict__ ptab, float* __restrict__ x) {
    int n = blockIdx.x, d = threadIdx.x;
    int tok = tokens[n], p = positions[n];
    x[n * D_ + d] = vtab[tok * D_ + d] * 16.0f + ctab[(p % 3) * D_ + d] + ptab[(p / 3) * D_ + d];
}

// one block per row, 256 threads == D
__global__ void ln_kernel(const float* __restrict__ x, const float* __restrict__ g,
                          const float* __restrict__ b, float* __restrict__ out) {
    __shared__ float r1[4], r2[4], mv[2];
    int n = blockIdx.x, t = threadIdx.x;
    float v = x[n * D_ + t];
    float s1 = v, s2 = v * v;
#pragma unroll
    for (int off = 32; off; off >>= 1) {
        s1 += __shfl_down(s1, off, 64);
        s2 += __shfl_down(s2, off, 64);
    }
    int w = t >> 6;
    if ((t & 63) == 0) { r1[w] = s1; r2[w] = s2; }
    __syncthreads();
    if (t == 0) {
        float a = r1[0] + r1[1] + r1[2] + r1[3];
        float c = r2[0] + r2[1] + r2[2] + r2[3];
        float mean = a * (1.0f / D_);
        float var = c * (1.0f / D_) - mean * mean;
        mv[0] = mean;
        mv[1] = rsqrtf(var + EPS_);
    }
    __syncthreads();
    out[n * D_ + t] = (v - mv[0]) * mv[1] * g[t] + b[t];
}

// 64x64 tile, BK=16, 256 threads, 4x4 micro-tile per thread. All dims multiples.
template <bool HAS_BIAS, bool HAS_RES, bool RELU>
__global__ void gemm_kernel(const float* __restrict__ A, const float* __restrict__ W,
                            const float* __restrict__ bias, const float* __restrict__ R,
                            float* __restrict__ C, int M, int K, int Nout) {
    __shared__ float As[16][64];   // [k][m]
    __shared__ float Bs[16][64];   // [k][n]
    int t = threadIdx.x;
    int m0 = blockIdx.x * 64, n0 = blockIdx.y * 64;
    int tx = t & 15, ty = t >> 4;
    int am = t & 63, ak = (t >> 6) << 2;   // A: row am, cols ak..ak+3
    int bk = t >> 4, bn = (t & 15) << 2;   // B: row bk, cols bn..bn+3
    float acc[4][4] = {};
    for (int k0 = 0; k0 < K; k0 += 16) {
        float4 av = *(const float4*)&A[(size_t)(m0 + am) * K + k0 + ak];
        float4 bv = *(const float4*)&W[(size_t)(k0 + bk) * Nout + n0 + bn];
        __syncthreads();
        As[ak + 0][am] = av.x;
        As[ak + 1][am] = av.y;
        As[ak + 2][am] = av.z;
        As[ak + 3][am] = av.w;
        *(float4*)&Bs[bk][bn] = bv;
        __syncthreads();
#pragma unroll
        for (int kk = 0; kk < 16; ++kk) {
            float4 a4 = *(const float4*)&As[kk][ty * 4];
            float4 b4 = *(const float4*)&Bs[kk][tx * 4];
            float ar[4] = {a4.x, a4.y, a4.z, a4.w};
            float br[4] = {b4.x, b4.y, b4.z, b4.w};
#pragma unroll
            for (int i = 0; i < 4; ++i)
#pragma unroll
                for (int jj = 0; jj < 4; ++jj) acc[i][jj] += ar[i] * br[jj];
        }
    }
#pragma unroll
    for (int i = 0; i < 4; ++i) {
        int row = m0 + ty * 4 + i;
        int col = n0 + tx * 4;
        float4 val = make_float4(acc[i][0], acc[i][1], acc[i][2], acc[i][3]);
        if (HAS_BIAS) {
            float4 bb = *(const float4*)&bias[col];
            val.x += bb.x; val.y += bb.y; val.z += bb.z; val.w += bb.w;
        }
        if (HAS_RES) {
            float4 r = *(const float4*)&R[(size_t)row * Nout + col];
            val.x += r.x; val.y += r.y; val.z += r.z; val.w += r.w;
        }
        if (RELU) {
            val.x = fmaxf(val.x, 0.f); val.y = fmaxf(val.y, 0.f);
            val.z = fmaxf(val.z, 0.f); val.w = fmaxf(val.w, 0.f);
        }
        *(float4*)&C[(size_t)row * Nout + col] = val;
    }
}

// one wave per (b,h,j): lanes = 2 srcs x 32 dims, shfl-reduced dot, online softmax
__global__ void attn_kernel(const float* __restrict__ q, const float* __restrict__ k,
                            const float* __restrict__ v, float* __restrict__ z) {
    int wid = (blockIdx.x * blockDim.x + threadIdx.x) >> 6;
    int lane = threadIdx.x & 63;
    int j = wid & (L_ - 1);
    int bh = wid >> 8;
    int h = bh & (H_ - 1);
    int b = bh >> 3;
    int d = lane & 31, s2 = lane >> 5;
    int base = h * DK_ + d;
    float qd = q[(size_t)(b * L_ + j) * D_ + base];
    float m = -INFINITY, den = 0.f, o = 0.f;
    for (int sb = 0; sb <= j; sb += 2) {
        int src = sb + s2;
        bool valid = src <= j;
        int srcS = valid ? src : j;
        float part = qd * k[(size_t)(b * L_ + srcS) * D_ + base];
#pragma unroll
        for (int off = 1; off < 32; off <<= 1) part += __shfl_xor(part, off, 32);
        if (valid) {
            float score = part * 0.17677669529663687f;  // 1/sqrt(32)
            float mn = fmaxf(m, score);
            float p = __expf(score - mn);
            float scale = __expf(m - mn);
            den = den * scale + p;
            o = o * scale + p * v[(size_t)(b * L_ + src) * D_ + base];
            m = mn;
        }
    }
    // merge the two 32-lane halves
    float m2 = __shfl_xor(m, 32, 64);
    float den2 = __shfl_xor(den, 32, 64);
    float o2 = __shfl_xor(o, 32, 64);
    float mn = fmaxf(m, m2);
    float sA = __expf(m - mn), sB = __expf(m2 - mn);
    float res = (o * sA + o2 * sB) / (den * sA + den2 * sB);
    if (s2 == 0) z[(size_t)(b * L_ + j) * D_ + base] = res;
}

// in-place log_softmax over V=2048, one block per row
__global__ void lsm_kernel(float* __restrict__ logits) {
    __shared__ float rm[4], rs[4];
    int row = blockIdx.x, t = threadIdx.x;
    float* p = logits + (size_t)row * V_;
    float vals[8];
    float mx = -INFINITY;
#pragma unroll
    for (int i = 0; i < 8; ++i) {
        vals[i] = p[t + i * 256];
        mx = fmaxf(mx, vals[i]);
    }
#pragma unroll
    for (int off = 32; off; off >>= 1) mx = fmaxf(mx, __shfl_xor(mx, off, 64));
    int w = t >> 6;
    if ((t & 63) == 0) rm[w] = mx;
    __syncthreads();
    mx = fmaxf(fmaxf(rm[0], rm[1]), fmaxf(rm[2], rm[3]));
    float s = 0.f;
#pragma unroll
    for (int i = 0; i < 8; ++i) s += __expf(vals[i] - mx);
#pragma unroll
    for (int off = 32; off; off >>= 1) s += __shfl_xor(s, off, 64);
    if ((t & 63) == 0) rs[w] = s;
    __syncthreads();
    s = rs[0] + rs[1] + rs[2] + rs[3];
    float lse = mx + logf(s);
#pragma unroll
    for (int i = 0; i < 8; ++i) p[t + i * 256] = vals[i] - lse;
}

extern "C" void kernel_launch(void* const* d_in, const int* in_sizes, int n_in,
                              void* d_out, int out_size, void* d_ws, size_t ws_size,
                              hipStream_t stream) {
    const int* tokens = (const int*)d_in[0];
    const int* positions = (const int*)d_in[1];
    // d_in[2]=src, d_in[3]=dst: edge structure is deterministic causal — unused
    const float* vtab = (const float*)d_in[4];
    const float* ctab = (const float*)d_in[5];
    const float* ptab = (const float*)d_in[6];
    const float* ln1_g = (const float*)d_in[7];
    const float* ln1_b = (const float*)d_in[8];
    const float* Wq = (const float*)d_in[9];
    const float* Wk = (const float*)d_in[10];
    const float* Wv = (const float*)d_in[11];
    const float* Wo = (const float*)d_in[12];
    const float* ln2_g = (const float*)d_in[13];
    const float* ln2_b = (const float*)d_in[14];
    const float* W1 = (const float*)d_in[15];
    const float* b1 = (const float*)d_in[16];
    const float* W2 = (const float*)d_in[17];
    const float* b2 = (const float*)d_in[18];
    const float* lnf_g = (const float*)d_in[19];
    const float* lnf_b = (const float*)d_in[20];
    const float* Wgen = (const float*)d_in[21];
    const float* bgen = (const float*)d_in[22];

    float* ws = (float*)d_ws;
    float* x = ws;                   // [N,D]
    float* xn = x + (size_t)N_ * D_; // [N,D]
    float* qb = xn + (size_t)N_ * D_;
    float* kb = qb + (size_t)N_ * D_;
    float* vb = kb + (size_t)N_ * D_;
    float* zb = vb + (size_t)N_ * D_;
    float* hb = qb;                  // FFN hidden [N,FF] reuses q/k/v/z (exactly 4*N*D)
    float* out = (float*)d_out;

    embed_kernel<<<N_, 256, 0, stream>>>(tokens, positions, vtab, ctab, ptab, x);
    dim3 gD(N_ / 64, D_ / 64);   // 32x4
    dim3 gF(N_ / 64, FF_ / 64);  // 32x16
    dim3 gV(N_ / 64, V_ / 64);   // 32x32
    for (int i = 0; i < NL_; ++i) {
        ln_kernel<<<N_, 256, 0, stream>>>(x, ln1_g + i * D_, ln1_b + i * D_, xn);
        gemm_kernel<false, false, false><<<gD, 256, 0, stream>>>(xn, Wq + (size_t)i * D_ * D_, nullptr, nullptr, qb, N_, D_, D_);
        gemm_kernel<false, false, false><<<gD, 256, 0, stream>>>(xn, Wk + (size_t)i * D_ * D_, nullptr, nullptr, kb, N_, D_, D_);
        gemm_kernel<false, false, false><<<gD, 256, 0, stream>>>(xn, Wv + (size_t)i * D_ * D_, nullptr, nullptr, vb, N_, D_, D_);
        attn_kernel<<<(B_ * H_ * L_) / 4, 256, 0, stream>>>(qb, kb, vb, zb);
        gemm_kernel<false, true, false><<<gD, 256, 0, stream>>>(zb, Wo + (size_t)i * D_ * D_, nullptr, x, x, N_, D_, D_);
        ln_kernel<<<N_, 256, 0, stream>>>(x, ln2_g + i * D_, ln2_b + i * D_, xn);
        gemm_kernel<true, false, true><<<gF, 256, 0, stream>>>(xn, W1 + (size_t)i * D_ * FF_, b1 + (size_t)i * FF_, nullptr, hb, N_, D_, FF_);
        gemm_kernel<true, true, false><<<gD, 256, 0, stream>>>(hb, W2 + (size_t)i * FF_ * D_, b2 + (size_t)i * D_, x, x, N_, FF_, D_);
    }
    ln_kernel<<<N_, 256, 0, stream>>>(x, lnf_g, lnf_b, xn);
    gemm_kernel<true, false, false><<<gV, 256, 0, stream>>>(xn, Wgen, bgen, nullptr, out, N_, D_, V_);
    lsm_kernel<<<N_, 256, 0, stream>>>(out);
}

// Round 2
// 975.513 us; speedup vs baseline: 1.4726x; 1.4726x over previous
//
#include <hip/hip_runtime.h>
#include <hip/hip_bf16.h>
#include <math.h>

constexpr int B_ = 8, L_ = 256, D_ = 256, H_ = 8, DK_ = 32, NL_ = 4, V_ = 2048, FF_ = 1024;
constexpr int N_ = B_ * L_;
constexpr float EPS_ = 1e-5f;

// x[n,d] = value_tab[tok]*sqrt(D) + coord_tab[p%3] + pos_tab[p/3]
__global__ void embed_kernel(const int* __restrict__ tokens, const int* __restrict__ positions,
                             const float* __restrict__ vtab, const float* __restrict__ ctab,
                             const float* __restrict__ ptab, float* __restrict__ x) {
    int n = blockIdx.x, d = threadIdx.x;
    int tok = tokens[n], p = positions[n];
    x[n * D_ + d] = vtab[tok * D_ + d] * 16.0f + ctab[(p % 3) * D_ + d] + ptab[(p / 3) * D_ + d];
}

// one block per row, 256 threads == D
__global__ void ln_kernel(const float* __restrict__ x, const float* __restrict__ g,
                          const float* __restrict__ b, float* __restrict__ out) {
    __shared__ float r1[4], r2[4], mv[2];
    int n = blockIdx.x, t = threadIdx.x;
    float v = x[n * D_ + t];
    float s1 = v, s2 = v * v;
#pragma unroll
    for (int off = 32; off; off >>= 1) {
        s1 += __shfl_down(s1, off, 64);
        s2 += __shfl_down(s2, off, 64);
    }
    int w = t >> 6;
    if ((t & 63) == 0) { r1[w] = s1; r2[w] = s2; }
    __syncthreads();
    if (t == 0) {
        float a = r1[0] + r1[1] + r1[2] + r1[3];
        float c = r2[0] + r2[1] + r2[2] + r2[3];
        float mean = a * (1.0f / D_);
        float var = c * (1.0f / D_) - mean * mean;
        mv[0] = mean;
        mv[1] = rsqrtf(var + EPS_);
    }
    __syncthreads();
    out[n * D_ + t] = (v - mv[0]) * mv[1] * g[t] + b[t];
}

// 64x64 tile, BK=16, 256 threads, 4x4 micro-tile per thread. All dims multiples.
template <bool HAS_BIAS, bool HAS_RES, bool RELU>
__global__ void gemm_kernel(const float* __restrict__ A, const float* __restrict__ W,
                            const float* __restrict__ bias, const float* __restrict__ R,
                            float* __restrict__ C, int M, int K, int Nout) {
    __shared__ float As[16][64];   // [k][m]
    __shared__ float Bs[16][64];   // [k][n]
    int t = threadIdx.x;
    int m0 = blockIdx.x * 64, n0 = blockIdx.y * 64;
    int tx = t & 15, ty = t >> 4;
    int am = t & 63, ak = (t >> 6) << 2;   // A: row am, cols ak..ak+3
    int bk = t >> 4, bn = (t & 15) << 2;   // B: row bk, cols bn..bn+3
    float acc[4][4] = {};
    for (int k0 = 0; k0 < K; k0 += 16) {
        float4 av = *(const float4*)&A[(size_t)(m0 + am) * K + k0 + ak];
        float4 bv = *(const float4*)&W[(size_t)(k0 + bk) * Nout + n0 + bn];
        __syncthreads();
        As[ak + 0][am] = av.x;
        As[ak + 1][am] = av.y;
        As[ak + 2][am] = av.z;
        As[ak + 3][am] = av.w;
        *(float4*)&Bs[bk][bn] = bv;
        __syncthreads();
#pragma unroll
        for (int kk = 0; kk < 16; ++kk) {
            float4 a4 = *(const float4*)&As[kk][ty * 4];
            float4 b4 = *(const float4*)&Bs[kk][tx * 4];
            float ar[4] = {a4.x, a4.y, a4.z, a4.w};
            float br[4] = {b4.x, b4.y, b4.z, b4.w};
#pragma unroll
            for (int i = 0; i < 4; ++i)
#pragma unroll
                for (int jj = 0; jj < 4; ++jj) acc[i][jj] += ar[i] * br[jj];
        }
    }
#pragma unroll
    for (int i = 0; i < 4; ++i) {
        int row = m0 + ty * 4 + i;
        int col = n0 + tx * 4;
        float4 val = make_float4(acc[i][0], acc[i][1], acc[i][2], acc[i][3]);
        if (HAS_BIAS) {
            float4 bb = *(const float4*)&bias[col];
            val.x += bb.x; val.y += bb.y; val.z += bb.z; val.w += bb.w;
        }
        if (HAS_RES) {
            float4 r = *(const float4*)&R[(size_t)row * Nout + col];
            val.x += r.x; val.y += r.y; val.z += r.z; val.w += r.w;
        }
        if (RELU) {
            val.x = fmaxf(val.x, 0.f); val.y = fmaxf(val.y, 0.f);
            val.z = fmaxf(val.z, 0.f); val.w = fmaxf(val.w, 0.f);
        }
        *(float4*)&C[(size_t)row * Nout + col] = val;
    }
}

// Flash-style attention. Block = (b,h, group of 4 queries), 4 waves, one wave per query.
// K/V staged in LDS per 64-source tile; lane = one source; online softmax per tile.
__global__ void attn_kernel(const float* __restrict__ q, const float* __restrict__ k,
                            const float* __restrict__ v, float* __restrict__ z) {
    __shared__ float Ks[64][36];   // stride 36 floats: 16B-aligned rows
    __shared__ float Vs[64][36];
    __shared__ float Obuf[4][32];
    int bh = blockIdx.x;           // 0..63
    int g = blockIdx.y;            // 0..63  -> queries 4g..4g+3
    int b = bh >> 3, h = bh & 7;
    int t = threadIdx.x, lane = t & 63, w = t >> 6;
    int j = g * 4 + w;             // this wave's query index

    const float* qrow = q + (size_t)(b * L_ + j) * D_ + h * DK_;
    float qreg[32];
#pragma unroll
    for (int d = 0; d < 32; ++d) qreg[d] = qrow[d];
    float o[32];
#pragma unroll
    for (int d = 0; d < 32; ++d) o[d] = 0.f;
    float m = -INFINITY, den = 0.f;

    int T = ((g * 4 + 3) >> 6) + 1;  // same tile count for all 4 waves in block
    int r = t >> 2, f0 = (t & 3) * 8;  // staging: thread loads row r, floats f0..f0+7
    for (int tt = 0; tt < T; ++tt) {
        __syncthreads();
        const float* gk = k + (size_t)(b * L_ + tt * 64 + r) * D_ + h * DK_ + f0;
        const float* gv = v + (size_t)(b * L_ + tt * 64 + r) * D_ + h * DK_ + f0;
        float4 ka = *(const float4*)gk;
        float4 kb2 = *(const float4*)(gk + 4);
        float4 va = *(const float4*)gv;
        float4 vb2 = *(const float4*)(gv + 4);
        *(float4*)&Ks[r][f0] = ka;
        *(float4*)&Ks[r][f0 + 4] = kb2;
        *(float4*)&Vs[r][f0] = va;
        *(float4*)&Vs[r][f0 + 4] = vb2;
        __syncthreads();

        int src = tt * 64 + lane;
        float sc = 0.f;
#pragma unroll
        for (int d4 = 0; d4 < 8; ++d4) {
            float4 kv = *(const float4*)&Ks[lane][d4 * 4];
            sc += qreg[d4 * 4 + 0] * kv.x + qreg[d4 * 4 + 1] * kv.y
                + qreg[d4 * 4 + 2] * kv.z + qreg[d4 * 4 + 3] * kv.w;
        }
        float score = (src <= j) ? sc * 0.17677669529663687f : -INFINITY;
        float tm = score;
#pragma unroll
        for (int off = 1; off < 64; off <<= 1) tm = fmaxf(tm, __shfl_xor(tm, off, 64));
        float mn = fmaxf(m, tm);
        float p = __expf(score - mn);   // -inf -> 0 for masked lanes
        float ts = p;
#pragma unroll
        for (int off = 1; off < 64; off <<= 1) ts += __shfl_xor(ts, off, 64);
        float scale = __expf(m - mn);   // first tile: exp(-inf)=0 zeroes stale state
        den = den * scale + ts;
        m = mn;
#pragma unroll
        for (int d4 = 0; d4 < 8; ++d4) {
            float4 vv = *(const float4*)&Vs[lane][d4 * 4];
            o[d4 * 4 + 0] = o[d4 * 4 + 0] * scale + p * vv.x;
            o[d4 * 4 + 1] = o[d4 * 4 + 1] * scale + p * vv.y;
            o[d4 * 4 + 2] = o[d4 * 4 + 2] * scale + p * vv.z;
            o[d4 * 4 + 3] = o[d4 * 4 + 3] * scale + p * vv.w;
        }
    }
    // cross-lane reduce of the 32-dim output (each lane holds partial over its sources)
#pragma unroll
    for (int off = 1; off < 64; off <<= 1) {
#pragma unroll
        for (int d = 0; d < 32; ++d) o[d] += __shfl_xor(o[d], off, 64);
    }
    float inv_den = 1.0f / den;  // den is wave-uniform after reduction
    if (lane == 0) {
#pragma unroll
        for (int d = 0; d < 32; ++d) Obuf[w][d] = o[d] * inv_den;
    }
    if (lane < 32) z[(size_t)(b * L_ + j) * D_ + h * DK_ + lane] = Obuf[w][lane];
}

// in-place log_softmax over V=2048, one block per row
__global__ void lsm_kernel(float* __restrict__ logits) {
    __shared__ float rm[4], rs[4];
    int row = blockIdx.x, t = threadIdx.x;
    float* p = logits + (size_t)row * V_;
    float vals[8];
    float mx = -INFINITY;
#pragma unroll
    for (int i = 0; i < 8; ++i) {
        vals[i] = p[t + i * 256];
        mx = fmaxf(mx, vals[i]);
    }
#pragma unroll
    for (int off = 32; off; off >>= 1) mx = fmaxf(mx, __shfl_xor(mx, off, 64));
    int w = t >> 6;
    if ((t & 63) == 0) rm[w] = mx;
    __syncthreads();
    mx = fmaxf(fmaxf(rm[0], rm[1]), fmaxf(rm[2], rm[3]));
    float s = 0.f;
#pragma unroll
    for (int i = 0; i < 8; ++i) s += __expf(vals[i] - mx);
#pragma unroll
    for (int off = 32; off; off >>= 1) s += __shfl_xor(s, off, 64);
    if ((t & 63) == 0) rs[w] = s;
    __syncthreads();
    s = rs[0] + rs[1] + rs[2] + rs[3];
    float lse = mx + logf(s);
#pragma unroll
    for (int i = 0; i < 8; ++i) p[t + i * 256] = vals[i] - lse;
}

extern "C" void kernel_launch(void* const* d_in, const int* in_sizes, int n_in,
                              void* d_out, int out_size, void* d_ws, size_t ws_size,
                              hipStream_t stream) {
    const int* tokens = (const int*)d_in[0];
    const int* positions = (const int*)d_in[1];
    // d_in[2]=src, d_in[3]=dst: edge structure is deterministic causal — unused
    const float* vtab = (const float*)d_in[4];
    const float* ctab = (const float*)d_in[5];
    const float* ptab = (const float*)d_in[6];
    const float* ln1_g = (const float*)d_in[7];
    const float* ln1_b = (const float*)d_in[8];
    const float* Wq = (const float*)d_in[9];
    const float* Wk = (const float*)d_in[10];
    const float* Wv = (const float*)d_in[11];
    const float* Wo = (const float*)d_in[12];
    const float* ln2_g = (const float*)d_in[13];
    const float* ln2_b = (const float*)d_in[14];
    const float* W1 = (const float*)d_in[15];
    const float* b1 = (const float*)d_in[16];
    const float* W2 = (const float*)d_in[17];
    const float* b2 = (const float*)d_in[18];
    const float* lnf_g = (const float*)d_in[19];
    const float* lnf_b = (const float*)d_in[20];
    const float* Wgen = (const float*)d_in[21];
    const float* bgen = (const float*)d_in[22];

    float* ws = (float*)d_ws;
    float* x = ws;                   // [N,D]
    float* xn = x + (size_t)N_ * D_; // [N,D]
    float* qb = xn + (size_t)N_ * D_;
    float* kb = qb + (size_t)N_ * D_;
    float* vb = kb + (size_t)N_ * D_;
    float* zb = vb + (size_t)N_ * D_;
    float* hb = qb;                  // FFN hidden [N,FF] reuses q/k/v/z (exactly 4*N*D)
    float* out = (float*)d_out;

    embed_kernel<<<N_, 256, 0, stream>>>(tokens, positions, vtab, ctab, ptab, x);
    dim3 gD(N_ / 64, D_ / 64);   // 32x4
    dim3 gF(N_ / 64, FF_ / 64);  // 32x16
    dim3 gV(N_ / 64, V_ / 64);   // 32x32
    dim3 gA(B_ * H_, L_ / 4);    // 64x64 blocks
    for (int i = 0; i < NL_; ++i) {
        ln_kernel<<<N_, 256, 0, stream>>>(x, ln1_g + i * D_, ln1_b + i * D_, xn);
        gemm_kernel<false, false, false><<<gD, 256, 0, stream>>>(xn, Wq + (size_t)i * D_ * D_, nullptr, nullptr, qb, N_, D_, D_);
        gemm_kernel<false, false, false><<<gD, 256, 0, stream>>>(xn, Wk + (size_t)i * D_ * D_, nullptr, nullptr, kb, N_, D_, D_);
        gemm_kernel<false, false, false><<<gD, 256, 0, stream>>>(xn, Wv + (size_t)i * D_ * D_, nullptr, nullptr, vb, N_, D_, D_);
        attn_kernel<<<gA, 256, 0, stream>>>(qb, kb, vb, zb);
        gemm_kernel<false, true, false><<<gD, 256, 0, stream>>>(zb, Wo + (size_t)i * D_ * D_, nullptr, x, x, N_, D_, D_);
        ln_kernel<<<N_, 256, 0, stream>>>(x, ln2_g + i * D_, ln2_b + i * D_, xn);
        gemm_kernel<true, false, true><<<gF, 256, 0, stream>>>(xn, W1 + (size_t)i * D_ * FF_, b1 + (size_t)i * FF_, nullptr, hb, N_, D_, FF_);
        gemm_kernel<true, true, false><<<gD, 256, 0, stream>>>(hb, W2 + (size_t)i * FF_ * D_, b2 + (size_t)i * D_, x, x, N_, FF_, D_);
    }
    ln_kernel<<<N_, 256, 0, stream>>>(x, lnf_g, lnf_b, xn);
    gemm_kernel<true, false, false><<<gV, 256, 0, stream>>>(xn, Wgen, bgen, nullptr, out, N_, D_, V_);
    lsm_kernel<<<N_, 256, 0, stream>>>(out);
}

// Round 3
// 501.286 us; speedup vs baseline: 2.8656x; 1.9460x over previous
//
#include <hip/hip_runtime.h>
#include <hip/hip_bf16.h>
#include <math.h>

constexpr int B_ = 8, L_ = 256, D_ = 256, H_ = 8, DK_ = 32, NL_ = 4, V_ = 2048, FF_ = 1024;
constexpr int N_ = B_ * L_;
constexpr float EPS_ = 1e-5f;

typedef short bf16x8 __attribute__((ext_vector_type(8)));
typedef float f32x4 __attribute__((ext_vector_type(4)));

__device__ __forceinline__ short f2b(float f) {
    union { __hip_bfloat16 h; short s; } u;
    u.h = __float2bfloat16(f);
    return u.s;
}

// x[n,d] = value_tab[tok]*sqrt(D) + coord_tab[p%3] + pos_tab[p/3]  (fp32 residual stream)
__global__ void embed_kernel(const int* __restrict__ tokens, const int* __restrict__ positions,
                             const float* __restrict__ vtab, const float* __restrict__ ctab,
                             const float* __restrict__ ptab, float* __restrict__ x) {
    int n = blockIdx.x, d = threadIdx.x;
    int tok = tokens[n], p = positions[n];
    x[n * D_ + d] = vtab[tok * D_ + d] * 16.0f + ctab[(p % 3) * D_ + d] + ptab[(p / 3) * D_ + d];
}

// LayerNorm, writes bf16 (all consumers are MFMA GEMMs)
__global__ void ln_kernel(const float* __restrict__ x, const float* __restrict__ g,
                          const float* __restrict__ b, short* __restrict__ out) {
    __shared__ float r1[4], r2[4], mv[2];
    int n = blockIdx.x, t = threadIdx.x;
    float v = x[n * D_ + t];
    float s1 = v, s2 = v * v;
#pragma unroll
    for (int off = 32; off; off >>= 1) {
        s1 += __shfl_down(s1, off, 64);
        s2 += __shfl_down(s2, off, 64);
    }
    int w = t >> 6;
    if ((t & 63) == 0) { r1[w] = s1; r2[w] = s2; }
    __syncthreads();
    if (t == 0) {
        float a = r1[0] + r1[1] + r1[2] + r1[3];
        float c = r2[0] + r2[1] + r2[2] + r2[3];
        float mean = a * (1.0f / D_);
        float var = c * (1.0f / D_) - mean * mean;
        mv[0] = mean;
        mv[1] = rsqrtf(var + EPS_);
    }
    __syncthreads();
    out[n * D_ + t] = f2b((v - mv[0]) * mv[1] * g[t] + b[t]);
}

// fp32 [K,N] -> bf16 [N,K] tiled transpose; batch via blockIdx.z
__global__ void transpose_w(const float* __restrict__ src, short* __restrict__ dst, int K, int Nn) {
    __shared__ float tile[32][33];
    int n0 = blockIdx.x * 32, k0 = blockIdx.y * 32;
    size_t base = (size_t)blockIdx.z * K * Nn;
    src += base;
    dst += base;
    int tx = threadIdx.x, ty = threadIdx.y;  // 32 x 8
#pragma unroll
    for (int i = 0; i < 32; i += 8)
        tile[ty + i][tx] = src[(size_t)(k0 + ty + i) * Nn + n0 + tx];
    __syncthreads();
#pragma unroll
    for (int i = 0; i < 32; i += 8)
        dst[(size_t)(n0 + ty + i) * K + k0 + tx] = f2b(tile[tx][ty + i]);
}

// 64x64 tile bf16 MFMA GEMM body. A:[M,K] bf16 row-major, Bt:[Nout,K] bf16 row-major.
// 4 waves, each 32x32 via 2x2 mfma_f32_16x16x32_bf16 fragments.
// EPI: 0 = store fp32; 1 = bias+relu -> bf16; 2 = atomicAdd fp32 (+bias from kz==0); 3 = bias -> fp32
template <int EPI, bool HAS_BIAS>
__device__ __forceinline__ void gemm_body(const short* __restrict__ A, const short* __restrict__ Bt,
                                          const float* __restrict__ bias, float* __restrict__ Cf,
                                          short* __restrict__ Cb, int M, int K, int Nout,
                                          int kbeg, int kend, int kz) {
    __shared__ short As[64][48];  // stride 48 shorts = 96B (16B-aligned rows, conflict-reduced)
    __shared__ short Bs[64][48];
    int t = threadIdx.x;
    int m0 = blockIdx.x * 64, n0 = blockIdx.y * 64;
    int sr = t >> 2, sc = (t & 3) * 8;
    int lane = t & 63, w = t >> 6;
    int mo = (w & 1) * 32, no = (w >> 1) * 32;
    int quad = lane >> 4, r = lane & 15;
    f32x4 acc00 = {}, acc01 = {}, acc10 = {}, acc11 = {};
    const short* Ap = &A[(size_t)(m0 + sr) * K + sc];
    const short* Bp = &Bt[(size_t)(n0 + sr) * K + sc];
    for (int k0 = kbeg; k0 < kend; k0 += 32) {
        int4 av = *(const int4*)(Ap + k0);
        int4 bv = *(const int4*)(Bp + k0);
        __syncthreads();
        *(int4*)&As[sr][sc] = av;
        *(int4*)&Bs[sr][sc] = bv;
        __syncthreads();
        bf16x8 a0 = *(const bf16x8*)&As[mo + r][quad * 8];
        bf16x8 a1 = *(const bf16x8*)&As[mo + 16 + r][quad * 8];
        bf16x8 b0 = *(const bf16x8*)&Bs[no + r][quad * 8];
        bf16x8 b1 = *(const bf16x8*)&Bs[no + 16 + r][quad * 8];
        acc00 = __builtin_amdgcn_mfma_f32_16x16x32_bf16(a0, b0, acc00, 0, 0, 0);
        acc01 = __builtin_amdgcn_mfma_f32_16x16x32_bf16(a0, b1, acc01, 0, 0, 0);
        acc10 = __builtin_amdgcn_mfma_f32_16x16x32_bf16(a1, b0, acc10, 0, 0, 0);
        acc11 = __builtin_amdgcn_mfma_f32_16x16x32_bf16(a1, b1, acc11, 0, 0, 0);
    }
#pragma unroll
    for (int i = 0; i < 2; ++i) {
#pragma unroll
        for (int j = 0; j < 2; ++j) {
            f32x4 acc = (i == 0) ? (j == 0 ? acc00 : acc01) : (j == 0 ? acc10 : acc11);
            int col = n0 + no + j * 16 + r;
            float bval = HAS_BIAS ? bias[col] : 0.f;
#pragma unroll
            for (int p = 0; p < 4; ++p) {
                int row = m0 + mo + i * 16 + quad * 4 + p;
                float v = acc[p];
                if (EPI == 0) {
                    Cf[(size_t)row * Nout + col] = v;
                } else if (EPI == 1) {
                    Cb[(size_t)row * Nout + col] = f2b(fmaxf(v + bval, 0.f));
                } else if (EPI == 2) {
                    float add = v + ((HAS_BIAS && kz == 0) ? bval : 0.f);
                    atomicAdd(&Cf[(size_t)row * Nout + col], add);
                } else {
                    Cf[(size_t)row * Nout + col] = v + bval;
                }
            }
        }
    }
}

// fused Q/K/V projection: blockIdx.z selects weight & destination
__global__ __launch_bounds__(256) void gemm_qkv(const short* __restrict__ A, const short* __restrict__ wq,
                                                const short* __restrict__ wk, const short* __restrict__ wv,
                                                float* __restrict__ q, float* __restrict__ k,
                                                float* __restrict__ v, int M, int K, int Nout) {
    const short* Bt = blockIdx.z == 0 ? wq : (blockIdx.z == 1 ? wk : wv);
    float* C = blockIdx.z == 0 ? q : (blockIdx.z == 1 ? k : v);
    gemm_body<0, false>(A, Bt, nullptr, C, nullptr, M, K, Nout, 0, K, 0);
}

// split-K accumulate into fp32 residual stream (bias applied by the kz==0 split only)
template <int SPLITK, bool HAS_BIAS>
__global__ __launch_bounds__(256) void gemm_accum(const short* __restrict__ A, const short* __restrict__ Bt,
                                                  const float* __restrict__ bias, float* __restrict__ C,
                                                  int M, int K, int Nout) {
    int Kp = K / SPLITK;
    int kz = blockIdx.z;
    gemm_body<2, HAS_BIAS>(A, Bt, bias, C, nullptr, M, K, Nout, kz * Kp, kz * Kp + Kp, kz);
}

__global__ __launch_bounds__(256) void gemm_biasrelu_bf16(const short* __restrict__ A,
                                                          const short* __restrict__ Bt,
                                                          const float* __restrict__ bias,
                                                          short* __restrict__ C, int M, int K, int Nout) {
    gemm_body<1, true>(A, Bt, bias, nullptr, C, M, K, Nout, 0, K, 0);
}

__global__ __launch_bounds__(256) void gemm_bias(const short* __restrict__ A, const short* __restrict__ Bt,
                                                 const float* __restrict__ bias, float* __restrict__ C,
                                                 int M, int K, int Nout) {
    gemm_body<3, true>(A, Bt, bias, C, nullptr, M, K, Nout, 0, K, 0);
}

// Flash-style attention. Block = (b,h, group of 4 queries), 4 waves, one wave per query.
// q,k,v fp32; output z bf16.
__global__ void attn_kernel(const float* __restrict__ q, const float* __restrict__ k,
                            const float* __restrict__ v, short* __restrict__ z) {
    __shared__ float Ks[64][36];
    __shared__ float Vs[64][36];
    __shared__ float Obuf[4][32];
    int bh = blockIdx.x;
    int g = blockIdx.y;
    int b = bh >> 3, h = bh & 7;
    int t = threadIdx.x, lane = t & 63, w = t >> 6;
    int j = g * 4 + w;

    const float* qrow = q + (size_t)(b * L_ + j) * D_ + h * DK_;
    float qreg[32];
#pragma unroll
    for (int d = 0; d < 32; ++d) qreg[d] = qrow[d];
    float o[32];
#pragma unroll
    for (int d = 0; d < 32; ++d) o[d] = 0.f;
    float m = -INFINITY, den = 0.f;

    int T = ((g * 4 + 3) >> 6) + 1;
    int r = t >> 2, f0 = (t & 3) * 8;
    for (int tt = 0; tt < T; ++tt) {
        __syncthreads();
        const float* gk = k + (size_t)(b * L_ + tt * 64 + r) * D_ + h * DK_ + f0;
        const float* gv = v + (size_t)(b * L_ + tt * 64 + r) * D_ + h * DK_ + f0;
        float4 ka = *(const float4*)gk;
        float4 kb2 = *(const float4*)(gk + 4);
        float4 va = *(const float4*)gv;
        float4 vb2 = *(const float4*)(gv + 4);
        *(float4*)&Ks[r][f0] = ka;
        *(float4*)&Ks[r][f0 + 4] = kb2;
        *(float4*)&Vs[r][f0] = va;
        *(float4*)&Vs[r][f0 + 4] = vb2;
        __syncthreads();

        int src = tt * 64 + lane;
        float sc = 0.f;
#pragma unroll
        for (int d4 = 0; d4 < 8; ++d4) {
            float4 kv = *(const float4*)&Ks[lane][d4 * 4];
            sc += qreg[d4 * 4 + 0] * kv.x + qreg[d4 * 4 + 1] * kv.y
                + qreg[d4 * 4 + 2] * kv.z + qreg[d4 * 4 + 3] * kv.w;
        }
        float score = (src <= j) ? sc * 0.17677669529663687f : -INFINITY;
        float tm = score;
#pragma unroll
        for (int off = 1; off < 64; off <<= 1) tm = fmaxf(tm, __shfl_xor(tm, off, 64));
        float mn = fmaxf(m, tm);
        float p = __expf(score - mn);
        float ts = p;
#pragma unroll
        for (int off = 1; off < 64; off <<= 1) ts += __shfl_xor(ts, off, 64);
        float scale = __expf(m - mn);
        den = den * scale + ts;
        m = mn;
#pragma unroll
        for (int d4 = 0; d4 < 8; ++d4) {
            float4 vv = *(const float4*)&Vs[lane][d4 * 4];
            o[d4 * 4 + 0] = o[d4 * 4 + 0] * scale + p * vv.x;
            o[d4 * 4 + 1] = o[d4 * 4 + 1] * scale + p * vv.y;
            o[d4 * 4 + 2] = o[d4 * 4 + 2] * scale + p * vv.z;
            o[d4 * 4 + 3] = o[d4 * 4 + 3] * scale + p * vv.w;
        }
    }
#pragma unroll
    for (int off = 1; off < 64; off <<= 1) {
#pragma unroll
        for (int d = 0; d < 32; ++d) o[d] += __shfl_xor(o[d], off, 64);
    }
    float inv_den = 1.0f / den;
    if (lane == 0) {
#pragma unroll
        for (int d = 0; d < 32; ++d) Obuf[w][d] = o[d] * inv_den;
    }
    if (lane < 32) z[(size_t)(b * L_ + j) * D_ + h * DK_ + lane] = f2b(Obuf[w][lane]);
}

// in-place log_softmax over V=2048, one block per row
__global__ void lsm_kernel(float* __restrict__ logits) {
    __shared__ float rm[4], rs[4];
    int row = blockIdx.x, t = threadIdx.x;
    float* p = logits + (size_t)row * V_;
    float vals[8];
    float mx = -INFINITY;
#pragma unroll
    for (int i = 0; i < 8; ++i) {
        vals[i] = p[t + i * 256];
        mx = fmaxf(mx, vals[i]);
    }
#pragma unroll
    for (int off = 32; off; off >>= 1) mx = fmaxf(mx, __shfl_xor(mx, off, 64));
    int w = t >> 6;
    if ((t & 63) == 0) rm[w] = mx;
    __syncthreads();
    mx = fmaxf(fmaxf(rm[0], rm[1]), fmaxf(rm[2], rm[3]));
    float s = 0.f;
#pragma unroll
    for (int i = 0; i < 8; ++i) s += __expf(vals[i] - mx);
#pragma unroll
    for (int off = 32; off; off >>= 1) s += __shfl_xor(s, off, 64);
    if ((t & 63) == 0) rs[w] = s;
    __syncthreads();
    s = rs[0] + rs[1] + rs[2] + rs[3];
    float lse = mx + logf(s);
#pragma unroll
    for (int i = 0; i < 8; ++i) p[t + i * 256] = vals[i] - lse;
}

extern "C" void kernel_launch(void* const* d_in, const int* in_sizes, int n_in,
                              void* d_out, int out_size, void* d_ws, size_t ws_size,
                              hipStream_t stream) {
    const int* tokens = (const int*)d_in[0];
    const int* positions = (const int*)d_in[1];
    // d_in[2]=src, d_in[3]=dst: deterministic causal structure — unused
    const float* vtab = (const float*)d_in[4];
    const float* ctab = (const float*)d_in[5];
    const float* ptab = (const float*)d_in[6];
    const float* ln1_g = (const float*)d_in[7];
    const float* ln1_b = (const float*)d_in[8];
    const float* Wq = (const float*)d_in[9];
    const float* Wk = (const float*)d_in[10];
    const float* Wv = (const float*)d_in[11];
    const float* Wo = (const float*)d_in[12];
    const float* ln2_g = (const float*)d_in[13];
    const float* ln2_b = (const float*)d_in[14];
    const float* W1 = (const float*)d_in[15];
    const float* b1 = (const float*)d_in[16];
    const float* W2 = (const float*)d_in[17];
    const float* b2 = (const float*)d_in[18];
    const float* lnf_g = (const float*)d_in[19];
    const float* lnf_b = (const float*)d_in[20];
    const float* Wgen = (const float*)d_in[21];
    const float* bgen = (const float*)d_in[22];

    char* p = (char*)d_ws;
    float* x = (float*)p;      p += (size_t)N_ * D_ * 4;
    float* qb = (float*)p;     p += (size_t)N_ * D_ * 4;
    float* kb = (float*)p;     p += (size_t)N_ * D_ * 4;
    float* vb = (float*)p;     p += (size_t)N_ * D_ * 4;
    short* xnb = (short*)p;    p += (size_t)N_ * D_ * 2;
    short* zbb = (short*)p;    p += (size_t)N_ * D_ * 2;
    short* hbb = (short*)p;    p += (size_t)N_ * FF_ * 2;
    short* wqT = (short*)p;    p += (size_t)NL_ * D_ * D_ * 2;
    short* wkT = (short*)p;    p += (size_t)NL_ * D_ * D_ * 2;
    short* wvT = (short*)p;    p += (size_t)NL_ * D_ * D_ * 2;
    short* woT = (short*)p;    p += (size_t)NL_ * D_ * D_ * 2;
    short* w1T = (short*)p;    p += (size_t)NL_ * D_ * FF_ * 2;
    short* w2T = (short*)p;    p += (size_t)NL_ * FF_ * D_ * 2;
    short* wgT = (short*)p;    p += (size_t)D_ * V_ * 2;
    float* out = (float*)d_out;

    // weight transpose+convert: fp32 [K,N] -> bf16 [N,K]
    dim3 tb(32, 8);
    transpose_w<<<dim3(8, 8, NL_), tb, 0, stream>>>(Wq, wqT, D_, D_);
    transpose_w<<<dim3(8, 8, NL_), tb, 0, stream>>>(Wk, wkT, D_, D_);
    transpose_w<<<dim3(8, 8, NL_), tb, 0, stream>>>(Wv, wvT, D_, D_);
    transpose_w<<<dim3(8, 8, NL_), tb, 0, stream>>>(Wo, woT, D_, D_);
    transpose_w<<<dim3(32, 8, NL_), tb, 0, stream>>>(W1, w1T, D_, FF_);
    transpose_w<<<dim3(8, 32, NL_), tb, 0, stream>>>(W2, w2T, FF_, D_);
    transpose_w<<<dim3(64, 8, 1), tb, 0, stream>>>(Wgen, wgT, D_, V_);

    embed_kernel<<<N_, 256, 0, stream>>>(tokens, positions, vtab, ctab, ptab, x);
    dim3 gQKV(N_ / 64, D_ / 64, 3);
    dim3 gWo(N_ / 64, D_ / 64, 2);
    dim3 gW1(N_ / 64, FF_ / 64);
    dim3 gW2(N_ / 64, D_ / 64, 4);
    dim3 gGen(N_ / 64, V_ / 64);
    dim3 gA(B_ * H_, L_ / 4);
    for (int i = 0; i < NL_; ++i) {
        ln_kernel<<<N_, 256, 0, stream>>>(x, ln1_g + i * D_, ln1_b + i * D_, xnb);
        gemm_qkv<<<gQKV, 256, 0, stream>>>(xnb, wqT + (size_t)i * D_ * D_, wkT + (size_t)i * D_ * D_,
                                           wvT + (size_t)i * D_ * D_, qb, kb, vb, N_, D_, D_);
        attn_kernel<<<gA, 256, 0, stream>>>(qb, kb, vb, zbb);
        gemm_accum<2, false><<<gWo, 256, 0, stream>>>(zbb, woT + (size_t)i * D_ * D_, nullptr, x, N_, D_, D_);
        ln_kernel<<<N_, 256, 0, stream>>>(x, ln2_g + i * D_, ln2_b + i * D_, xnb);
        gemm_biasrelu_bf16<<<gW1, 256, 0, stream>>>(xnb, w1T + (size_t)i * D_ * FF_, b1 + (size_t)i * FF_,
                                                    hbb, N_, D_, FF_);
        gemm_accum<4, true><<<gW2, 256, 0, stream>>>(hbb, w2T + (size_t)i * FF_ * D_, b2 + (size_t)i * D_,
                                                     x, N_, FF_, D_);
    }
    ln_kernel<<<N_, 256, 0, stream>>>(x, lnf_g, lnf_b, xnb);
    gemm_bias<<<gGen, 256, 0, stream>>>(xnb, wgT, bgen, out, N_, D_, V_);
    lsm_kernel<<<N_, 256, 0, stream>>>(out);
}

// Round 4
// 337.650 us; speedup vs baseline: 4.2544x; 1.4846x over previous
//
#include <hip/hip_runtime.h>
#include <hip/hip_bf16.h>
#include <math.h>

constexpr int B_ = 8, L_ = 256, D_ = 256, H_ = 8, DK_ = 32, NL_ = 4, V_ = 2048, FF_ = 1024;
constexpr int N_ = B_ * L_;
constexpr float EPS_ = 1e-5f;

typedef short bf16x8 __attribute__((ext_vector_type(8)));
typedef float f32x4 __attribute__((ext_vector_type(4)));
typedef _Float16 f16x4 __attribute__((ext_vector_type(4)));

__device__ __forceinline__ short f2b(float f) {
    union { __hip_bfloat16 h; short s; } u;
    u.h = __float2bfloat16(f);
    return u.s;
}

// x[n,d] = value_tab[tok]*sqrt(D) + coord_tab[p%3] + pos_tab[p/3]  (fp32 residual stream)
__global__ void embed_kernel(const int* __restrict__ tokens, const int* __restrict__ positions,
                             const float* __restrict__ vtab, const float* __restrict__ ctab,
                             const float* __restrict__ ptab, float* __restrict__ x) {
    int n = blockIdx.x, d = threadIdx.x;
    int tok = tokens[n], p = positions[n];
    x[n * D_ + d] = vtab[tok * D_ + d] * 16.0f + ctab[(p % 3) * D_ + d] + ptab[(p / 3) * D_ + d];
}

// LayerNorm, writes bf16 (all consumers are MFMA GEMMs)
__global__ void ln_kernel(const float* __restrict__ x, const float* __restrict__ g,
                          const float* __restrict__ b, short* __restrict__ out) {
    __shared__ float r1[4], r2[4], mv[2];
    int n = blockIdx.x, t = threadIdx.x;
    float v = x[n * D_ + t];
    float s1 = v, s2 = v * v;
#pragma unroll
    for (int off = 32; off; off >>= 1) {
        s1 += __shfl_down(s1, off, 64);
        s2 += __shfl_down(s2, off, 64);
    }
    int w = t >> 6;
    if ((t & 63) == 0) { r1[w] = s1; r2[w] = s2; }
    __syncthreads();
    if (t == 0) {
        float a = r1[0] + r1[1] + r1[2] + r1[3];
        float c = r2[0] + r2[1] + r2[2] + r2[3];
        float mean = a * (1.0f / D_);
        float var = c * (1.0f / D_) - mean * mean;
        mv[0] = mean;
        mv[1] = rsqrtf(var + EPS_);
    }
    __syncthreads();
    out[n * D_ + t] = f2b((v - mv[0]) * mv[1] * g[t] + b[t]);
}

// fp32 [K,N] -> bf16 [N,K] tiled transpose; batch via blockIdx.z
__global__ void transpose_w(const float* __restrict__ src, short* __restrict__ dst, int K, int Nn) {
    __shared__ float tile[32][33];
    int n0 = blockIdx.x * 32, k0 = blockIdx.y * 32;
    size_t base = (size_t)blockIdx.z * K * Nn;
    src += base;
    dst += base;
    int tx = threadIdx.x, ty = threadIdx.y;  // 32 x 8
#pragma unroll
    for (int i = 0; i < 32; i += 8)
        tile[ty + i][tx] = src[(size_t)(k0 + ty + i) * Nn + n0 + tx];
    __syncthreads();
#pragma unroll
    for (int i = 0; i < 32; i += 8)
        dst[(size_t)(n0 + ty + i) * K + k0 + tx] = f2b(tile[tx][ty + i]);
}

// 64x64 tile bf16 MFMA GEMM body. A:[M,K] bf16 row-major, Bt:[Nout,K] bf16 row-major.
// EPI: 0 = store fp32; 1 = bias+relu -> bf16; 2 = atomicAdd fp32 (+bias from kz==0);
//      3 = bias -> fp32; 4 = store bf16; 5 = store f16
template <int EPI, bool HAS_BIAS>
__device__ __forceinline__ void gemm_body(const short* __restrict__ A, const short* __restrict__ Bt,
                                          const float* __restrict__ bias, float* __restrict__ Cf,
                                          short* __restrict__ Cb, int M, int K, int Nout,
                                          int kbeg, int kend, int kz) {
    __shared__ short As[64][48];
    __shared__ short Bs[64][48];
    int t = threadIdx.x;
    int m0 = blockIdx.x * 64, n0 = blockIdx.y * 64;
    int sr = t >> 2, sc = (t & 3) * 8;
    int lane = t & 63, w = t >> 6;
    int mo = (w & 1) * 32, no = (w >> 1) * 32;
    int quad = lane >> 4, r = lane & 15;
    f32x4 acc00 = {}, acc01 = {}, acc10 = {}, acc11 = {};
    const short* Ap = &A[(size_t)(m0 + sr) * K + sc];
    const short* Bp = &Bt[(size_t)(n0 + sr) * K + sc];
    for (int k0 = kbeg; k0 < kend; k0 += 32) {
        int4 av = *(const int4*)(Ap + k0);
        int4 bv = *(const int4*)(Bp + k0);
        __syncthreads();
        *(int4*)&As[sr][sc] = av;
        *(int4*)&Bs[sr][sc] = bv;
        __syncthreads();
        bf16x8 a0 = *(const bf16x8*)&As[mo + r][quad * 8];
        bf16x8 a1 = *(const bf16x8*)&As[mo + 16 + r][quad * 8];
        bf16x8 b0 = *(const bf16x8*)&Bs[no + r][quad * 8];
        bf16x8 b1 = *(const bf16x8*)&Bs[no + 16 + r][quad * 8];
        acc00 = __builtin_amdgcn_mfma_f32_16x16x32_bf16(a0, b0, acc00, 0, 0, 0);
        acc01 = __builtin_amdgcn_mfma_f32_16x16x32_bf16(a0, b1, acc01, 0, 0, 0);
        acc10 = __builtin_amdgcn_mfma_f32_16x16x32_bf16(a1, b0, acc10, 0, 0, 0);
        acc11 = __builtin_amdgcn_mfma_f32_16x16x32_bf16(a1, b1, acc11, 0, 0, 0);
    }
#pragma unroll
    for (int i = 0; i < 2; ++i) {
#pragma unroll
        for (int j = 0; j < 2; ++j) {
            f32x4 acc = (i == 0) ? (j == 0 ? acc00 : acc01) : (j == 0 ? acc10 : acc11);
            int col = n0 + no + j * 16 + r;
            float bval = HAS_BIAS ? bias[col] : 0.f;
#pragma unroll
            for (int p = 0; p < 4; ++p) {
                int row = m0 + mo + i * 16 + quad * 4 + p;
                float v = acc[p];
                if (EPI == 0) {
                    Cf[(size_t)row * Nout + col] = v;
                } else if (EPI == 1) {
                    Cb[(size_t)row * Nout + col] = f2b(fmaxf(v + bval, 0.f));
                } else if (EPI == 2) {
                    float add = v + ((HAS_BIAS && kz == 0) ? bval : 0.f);
                    atomicAdd(&Cf[(size_t)row * Nout + col], add);
                } else if (EPI == 3) {
                    Cf[(size_t)row * Nout + col] = v + bval;
                } else if (EPI == 4) {
                    Cb[(size_t)row * Nout + col] = f2b(v);
                } else {
                    ((_Float16*)Cb)[(size_t)row * Nout + col] = (_Float16)v;
                }
            }
        }
    }
}

// fused Q/K/V projection: q,k -> bf16; v -> f16 (PV mfma uses f16)
__global__ __launch_bounds__(256) void gemm_qkv(const short* __restrict__ A, const short* __restrict__ wq,
                                                const short* __restrict__ wk, const short* __restrict__ wv,
                                                short* __restrict__ q, short* __restrict__ k,
                                                short* __restrict__ v, int M, int K, int Nout) {
    if (blockIdx.z == 0)
        gemm_body<4, false>(A, wq, nullptr, nullptr, q, M, K, Nout, 0, K, 0);
    else if (blockIdx.z == 1)
        gemm_body<4, false>(A, wk, nullptr, nullptr, k, M, K, Nout, 0, K, 0);
    else
        gemm_body<5, false>(A, wv, nullptr, nullptr, v, M, K, Nout, 0, K, 0);
}

template <int SPLITK, bool HAS_BIAS>
__global__ __launch_bounds__(256) void gemm_accum(const short* __restrict__ A, const short* __restrict__ Bt,
                                                  const float* __restrict__ bias, float* __restrict__ C,
                                                  int M, int K, int Nout) {
    int Kp = K / SPLITK;
    int kz = blockIdx.z;
    gemm_body<2, HAS_BIAS>(A, Bt, bias, C, nullptr, M, K, Nout, kz * Kp, kz * Kp + Kp, kz);
}

__global__ __launch_bounds__(256) void gemm_biasrelu_bf16(const short* __restrict__ A,
                                                          const short* __restrict__ Bt,
                                                          const float* __restrict__ bias,
                                                          short* __restrict__ C, int M, int K, int Nout) {
    gemm_body<1, true>(A, Bt, bias, nullptr, C, M, K, Nout, 0, K, 0);
}

__global__ __launch_bounds__(256) void gemm_bias(const short* __restrict__ A, const short* __restrict__ Bt,
                                                 const float* __restrict__ bias, float* __restrict__ C,
                                                 int M, int K, int Nout) {
    gemm_body<3, true>(A, Bt, bias, C, nullptr, M, K, Nout, 0, K, 0);
}

// MFMA flash attention. One wave (64 thr) per (b,h,q-tile of 16 queries).
// S^T = K·Q^T via mfma_16x16x32_bf16 -> C layout (q=lane&15, src=quad*4+reg)
// which IS the A-layout of mfma_16x16x16f16 -> PV with no transpose.
__global__ __launch_bounds__(64) void attn_kernel(const short* __restrict__ q,
                                                  const short* __restrict__ k,
                                                  const _Float16* __restrict__ v,
                                                  short* __restrict__ z) {
    int blk = blockIdx.x;
    int bh = blk & 63;
    int qt = 15 - (blk >> 6);  // heavy q-tiles dispatched first
    int b = bh >> 3, h = bh & 7;
    int lane = threadIdx.x;
    int r = lane & 15, quad = lane >> 4;
    int row0 = b * L_;

    // Q fragment (B operand): Q[qt*16+r][h*32 + quad*8 ..+7]
    bf16x8 qf = *(const bf16x8*)&q[(size_t)(row0 + qt * 16 + r) * D_ + h * DK_ + quad * 8];
    f32x4 O0 = {}, O1 = {};
    float mA = -1e30f, den = 0.f;
    int nk = qt + 1;

    // prefetch k-tile 0
    bf16x8 kf = *(const bf16x8*)&k[(size_t)(row0 + r) * D_ + h * DK_ + quad * 8];
    f16x4 va, vb;
    {
        const _Float16* vp = v + (size_t)(row0 + quad * 4) * D_ + h * DK_;
#pragma unroll
        for (int i = 0; i < 4; ++i) {
            va[i] = vp[(size_t)i * D_ + r];
            vb[i] = vp[(size_t)i * D_ + 16 + r];
        }
    }
    for (int kt = 0; kt < nk; ++kt) {
        bf16x8 kf_n = kf;
        f16x4 va_n = va, vb_n = vb;
        if (kt + 1 < nk) {
            kf_n = *(const bf16x8*)&k[(size_t)(row0 + (kt + 1) * 16 + r) * D_ + h * DK_ + quad * 8];
            const _Float16* vp = v + (size_t)(row0 + (kt + 1) * 16 + quad * 4) * D_ + h * DK_;
#pragma unroll
            for (int i = 0; i < 4; ++i) {
                va_n[i] = vp[(size_t)i * D_ + r];
                vb_n[i] = vp[(size_t)i * D_ + 16 + r];
            }
        }
        f32x4 zero = {};
        f32x4 s = __builtin_amdgcn_mfma_f32_16x16x32_bf16(kf, qf, zero, 0, 0, 0);
#pragma unroll
        for (int i2 = 0; i2 < 4; ++i2) s[i2] *= 0.17677669529663687f;
        if (kt == qt) {  // diagonal tile: mask src_local > q_local
#pragma unroll
            for (int i2 = 0; i2 < 4; ++i2)
                if (quad * 4 + i2 > r) s[i2] = -1e30f;
        }
        float tmax = fmaxf(fmaxf(s[0], s[1]), fmaxf(s[2], s[3]));
        tmax = fmaxf(tmax, __shfl_xor(tmax, 16, 64));
        tmax = fmaxf(tmax, __shfl_xor(tmax, 32, 64));
        float mn = fmaxf(mA, tmax);
        float alpha = __expf(mA - mn);
        mA = mn;
        float p0 = __expf(s[0] - mn), p1 = __expf(s[1] - mn);
        float p2 = __expf(s[2] - mn), p3 = __expf(s[3] - mn);
        float ts = (p0 + p1) + (p2 + p3);
        ts += __shfl_xor(ts, 16, 64);
        ts += __shfl_xor(ts, 32, 64);
        den = den * alpha + ts;
        f16x4 pf;
        pf[0] = (_Float16)p0; pf[1] = (_Float16)p1; pf[2] = (_Float16)p2; pf[3] = (_Float16)p3;
        float al[4];
#pragma unroll
        for (int i2 = 0; i2 < 4; ++i2) al[i2] = __shfl(alpha, quad * 4 + i2, 64);
#pragma unroll
        for (int i2 = 0; i2 < 4; ++i2) { O0[i2] *= al[i2]; O1[i2] *= al[i2]; }
        O0 = __builtin_amdgcn_mfma_f32_16x16x16f16(pf, va, O0, 0, 0, 0);
        O1 = __builtin_amdgcn_mfma_f32_16x16x16f16(pf, vb, O1, 0, 0, 0);
        kf = kf_n; va = va_n; vb = vb_n;
    }
#pragma unroll
    for (int i2 = 0; i2 < 4; ++i2) {
        float inv = 1.0f / __shfl(den, quad * 4 + i2, 64);
        int rowz = row0 + qt * 16 + quad * 4 + i2;
        z[(size_t)rowz * D_ + h * DK_ + r] = f2b(O0[i2] * inv);
        z[(size_t)rowz * D_ + h * DK_ + 16 + r] = f2b(O1[i2] * inv);
    }
}

// in-place log_softmax over V=2048, one block per row
__global__ void lsm_kernel(float* __restrict__ logits) {
    __shared__ float rm[4], rs[4];
    int row = blockIdx.x, t = threadIdx.x;
    float* p = logits + (size_t)row * V_;
    float vals[8];
    float mx = -INFINITY;
#pragma unroll
    for (int i = 0; i < 8; ++i) {
        vals[i] = p[t + i * 256];
        mx = fmaxf(mx, vals[i]);
    }
#pragma unroll
    for (int off = 32; off; off >>= 1) mx = fmaxf(mx, __shfl_xor(mx, off, 64));
    int w = t >> 6;
    if ((t & 63) == 0) rm[w] = mx;
    __syncthreads();
    mx = fmaxf(fmaxf(rm[0], rm[1]), fmaxf(rm[2], rm[3]));
    float s = 0.f;
#pragma unroll
    for (int i = 0; i < 8; ++i) s += __expf(vals[i] - mx);
#pragma unroll
    for (int off = 32; off; off >>= 1) s += __shfl_xor(s, off, 64);
    if ((t & 63) == 0) rs[w] = s;
    __syncthreads();
    s = rs[0] + rs[1] + rs[2] + rs[3];
    float lse = mx + logf(s);
#pragma unroll
    for (int i = 0; i < 8; ++i) p[t + i * 256] = vals[i] - lse;
}

extern "C" void kernel_launch(void* const* d_in, const int* in_sizes, int n_in,
                              void* d_out, int out_size, void* d_ws, size_t ws_size,
                              hipStream_t stream) {
    const int* tokens = (const int*)d_in[0];
    const int* positions = (const int*)d_in[1];
    // d_in[2]=src, d_in[3]=dst: deterministic causal structure — unused
    const float* vtab = (const float*)d_in[4];
    const float* ctab = (const float*)d_in[5];
    const float* ptab = (const float*)d_in[6];
    const float* ln1_g = (const float*)d_in[7];
    const float* ln1_b = (const float*)d_in[8];
    const float* Wq = (const float*)d_in[9];
    const float* Wk = (const float*)d_in[10];
    const float* Wv = (const float*)d_in[11];
    const float* Wo = (const float*)d_in[12];
    const float* ln2_g = (const float*)d_in[13];
    const float* ln2_b = (const float*)d_in[14];
    const float* W1 = (const float*)d_in[15];
    const float* b1 = (const float*)d_in[16];
    const float* W2 = (const float*)d_in[17];
    const float* b2 = (const float*)d_in[18];
    const float* lnf_g = (const float*)d_in[19];
    const float* lnf_b = (const float*)d_in[20];
    const float* Wgen = (const float*)d_in[21];
    const float* bgen = (const float*)d_in[22];

    char* p = (char*)d_ws;
    float* x = (float*)p;      p += (size_t)N_ * D_ * 4;
    short* qb = (short*)p;     p += (size_t)N_ * D_ * 4;   // bf16 (padded alloc)
    short* kb = (short*)p;     p += (size_t)N_ * D_ * 4;   // bf16
    short* vbh = (short*)p;    p += (size_t)N_ * D_ * 4;   // f16
    short* xnb = (short*)p;    p += (size_t)N_ * D_ * 2;
    short* zbb = (short*)p;    p += (size_t)N_ * D_ * 2;
    short* hbb = (short*)p;    p += (size_t)N_ * FF_ * 2;
    short* wqT = (short*)p;    p += (size_t)NL_ * D_ * D_ * 2;
    short* wkT = (short*)p;    p += (size_t)NL_ * D_ * D_ * 2;
    short* wvT = (short*)p;    p += (size_t)NL_ * D_ * D_ * 2;
    short* woT = (short*)p;    p += (size_t)NL_ * D_ * D_ * 2;
    short* w1T = (short*)p;    p += (size_t)NL_ * D_ * FF_ * 2;
    short* w2T = (short*)p;    p += (size_t)NL_ * FF_ * D_ * 2;
    short* wgT = (short*)p;    p += (size_t)D_ * V_ * 2;
    float* out = (float*)d_out;

    dim3 tb(32, 8);
    transpose_w<<<dim3(8, 8, NL_), tb, 0, stream>>>(Wq, wqT, D_, D_);
    transpose_w<<<dim3(8, 8, NL_), tb, 0, stream>>>(Wk, wkT, D_, D_);
    transpose_w<<<dim3(8, 8, NL_), tb, 0, stream>>>(Wv, wvT, D_, D_);
    transpose_w<<<dim3(8, 8, NL_), tb, 0, stream>>>(Wo, woT, D_, D_);
    transpose_w<<<dim3(32, 8, NL_), tb, 0, stream>>>(W1, w1T, D_, FF_);
    transpose_w<<<dim3(8, 32, NL_), tb, 0, stream>>>(W2, w2T, FF_, D_);
    transpose_w<<<dim3(64, 8, 1), tb, 0, stream>>>(Wgen, wgT, D_, V_);

    embed_kernel<<<N_, 256, 0, stream>>>(tokens, positions, vtab, ctab, ptab, x);
    dim3 gQKV(N_ / 64, D_ / 64, 3);
    dim3 gWo(N_ / 64, D_ / 64, 2);
    dim3 gW1(N_ / 64, FF_ / 64);
    dim3 gW2(N_ / 64, D_ / 64, 4);
    dim3 gGen(N_ / 64, V_ / 64);
    for (int i = 0; i < NL_; ++i) {
        ln_kernel<<<N_, 256, 0, stream>>>(x, ln1_g + i * D_, ln1_b + i * D_, xnb);
        gemm_qkv<<<gQKV, 256, 0, stream>>>(xnb, wqT + (size_t)i * D_ * D_, wkT + (size_t)i * D_ * D_,
                                           wvT + (size_t)i * D_ * D_, qb, kb, vbh, N_, D_, D_);
        attn_kernel<<<B_ * H_ * 16, 64, 0, stream>>>(qb, kb, (const _Float16*)vbh, zbb);
        gemm_accum<2, false><<<gWo, 256, 0, stream>>>(zbb, woT + (size_t)i * D_ * D_, nullptr, x, N_, D_, D_);
        ln_kernel<<<N_, 256, 0, stream>>>(x, ln2_g + i * D_, ln2_b + i * D_, xnb);
        gemm_biasrelu_bf16<<<gW1, 256, 0, stream>>>(xnb, w1T + (size_t)i * D_ * FF_, b1 + (size_t)i * FF_,
                                                    hbb, N_, D_, FF_);
        gemm_accum<4, true><<<gW2, 256, 0, stream>>>(hbb, w2T + (size_t)i * FF_ * D_, b2 + (size_t)i * D_,
                                                     x, N_, FF_, D_);
    }
    ln_kernel<<<N_, 256, 0, stream>>>(x, lnf_g, lnf_b, xnb);
    gemm_bias<<<gGen, 256, 0, stream>>>(xnb, wgT, bgen, out, N_, D_, V_);
    lsm_kernel<<<N_, 256, 0, stream>>>(out);
}